// Round 2
// baseline (816.199 us; speedup 1.0000x reference)
//
#include <hip/hip_runtime.h>

// SparseAttention: q/k projection -> per-head softmax -> head-avg -> threshold>0.1
// -> renorm -> sparse (<=9 nnz/row guaranteed) PV against raw value tensor.
// L=1024, B=8, E=512, H=8, D=64, S=1024. All fp32 (round-1 correctness baseline).

#define THRESH 0.1f

// ---------------------------------------------------------------------------
// K1: projection GEMM  out = A @ W^T + bias, scattered to [B][H][L][D]
// A: (M=8192, K=512) row-major, rows are (l,b) pairs (l*8+b). W: (512,512).
// 128x128 tile, BK=16, 256 threads, 8x8 microtile.
// ---------------------------------------------------------------------------
__global__ __launch_bounds__(256) void proj_kernel(
    const float* __restrict__ A,
    const float* __restrict__ W,
    const float* __restrict__ bias,
    float* __restrict__ outp)
{
  __shared__ float As[16][132];
  __shared__ float Ws[16][132];
  const int t  = threadIdx.x;
  const int bm = blockIdx.x;     // 0..63
  const int bn = blockIdx.y;     // 0..3
  const int ty = t >> 4;         // 0..15
  const int tx = t & 15;         // 0..15
  const int lr  = t >> 2;        // 0..63
  const int lc4 = (t & 3) << 2;  // 0,4,8,12

  const float* Arow0 = A + (size_t)(bm * 128 + lr) * 512 + lc4;
  const float* Arow1 = Arow0 + 64 * 512;
  const float* Wrow0 = W + (size_t)(bn * 128 + lr) * 512 + lc4;
  const float* Wrow1 = Wrow0 + 64 * 512;

  float acc[8][8] = {};

  for (int k0 = 0; k0 < 512; k0 += 16) {
    float4 a0 = *(const float4*)(Arow0 + k0);
    float4 a1 = *(const float4*)(Arow1 + k0);
    float4 w0 = *(const float4*)(Wrow0 + k0);
    float4 w1 = *(const float4*)(Wrow1 + k0);
    __syncthreads();
    As[lc4 + 0][lr] = a0.x; As[lc4 + 1][lr] = a0.y; As[lc4 + 2][lr] = a0.z; As[lc4 + 3][lr] = a0.w;
    As[lc4 + 0][lr + 64] = a1.x; As[lc4 + 1][lr + 64] = a1.y; As[lc4 + 2][lr + 64] = a1.z; As[lc4 + 3][lr + 64] = a1.w;
    Ws[lc4 + 0][lr] = w0.x; Ws[lc4 + 1][lr] = w0.y; Ws[lc4 + 2][lr] = w0.z; Ws[lc4 + 3][lr] = w0.w;
    Ws[lc4 + 0][lr + 64] = w1.x; Ws[lc4 + 1][lr + 64] = w1.y; Ws[lc4 + 2][lr + 64] = w1.z; Ws[lc4 + 3][lr + 64] = w1.w;
    __syncthreads();
    #pragma unroll
    for (int kk = 0; kk < 16; ++kk) {
      float4 av0 = *(const float4*)&As[kk][ty * 8];
      float4 av1 = *(const float4*)&As[kk][ty * 8 + 4];
      float4 bv0 = *(const float4*)&Ws[kk][tx * 8];
      float4 bv1 = *(const float4*)&Ws[kk][tx * 8 + 4];
      float ar[8] = {av0.x, av0.y, av0.z, av0.w, av1.x, av1.y, av1.z, av1.w};
      float br[8] = {bv0.x, bv0.y, bv0.z, bv0.w, bv1.x, bv1.y, bv1.z, bv1.w};
      #pragma unroll
      for (int i = 0; i < 8; ++i)
        #pragma unroll
        for (int j = 0; j < 8; ++j)
          acc[i][j] += ar[i] * br[j];
    }
  }

  #pragma unroll
  for (int i = 0; i < 8; ++i) {
    const int gr = bm * 128 + ty * 8 + i;
    const int l = gr >> 3;
    const int b = gr & 7;
    #pragma unroll
    for (int jv = 0; jv < 8; jv += 4) {
      const int gc = bn * 128 + tx * 8 + jv;
      const int h = gc >> 6;
      const int d = gc & 63;
      float4 v;
      v.x = acc[i][jv + 0] + bias[gc + 0];
      v.y = acc[i][jv + 1] + bias[gc + 1];
      v.z = acc[i][jv + 2] + bias[gc + 2];
      v.w = acc[i][jv + 3] + bias[gc + 3];
      *(float4*)&outp[(size_t)((b * 8 + h) * 1024 + l) * 64 + d] = v;
    }
  }
}

// ---------------------------------------------------------------------------
// K2: fused scores + softmax + head-average + threshold + renormalize.
// Grid (L/8, B), 256 threads. Thread: row r = t>>5 (of 8), 32 s-values
// strided by 32 (s = 32*i + c, c = t&31). q row in regs; k staged in LDS.
// Softmax reduces across the 32 lanes sharing a row via shfl_xor.
// Writes final sw[B][L][S] (second output) directly.
// ---------------------------------------------------------------------------
__global__ __launch_bounds__(256) void attn_kernel(
    const float* __restrict__ qws,   // [B][H][L][64]
    const float* __restrict__ kws,   // [B][H][S][64]
    float* __restrict__ sw)          // [B][L][S]
{
  const int l0 = blockIdx.x * 8;
  const int b  = blockIdx.y;
  const int t  = threadIdx.x;
  const int r  = t >> 5;   // 0..7
  const int c  = t & 31;   // 0..31

  __shared__ float Ks[64][68];

  float acc[32];
  #pragma unroll
  for (int i = 0; i < 32; ++i) acc[i] = 0.f;

  for (int h = 0; h < 8; ++h) {
    const float* qrow = qws + (size_t)((b * 8 + h) * 1024 + l0 + r) * 64;
    float4 qv[16];
    #pragma unroll
    for (int d4 = 0; d4 < 16; ++d4) qv[d4] = *(const float4*)(qrow + d4 * 4);

    const float* kbase = kws + (size_t)((b * 8 + h) * 1024) * 64;
    float sc[32];
    for (int st = 0; st < 16; ++st) {
      __syncthreads();
      #pragma unroll
      for (int it = 0; it < 4; ++it) {
        const int idx = t + it * 256;     // 0..1023
        const int kr  = idx >> 4;         // 0..63
        const int c4  = (idx & 15) << 2;  // 0..60
        float4 kv = *(const float4*)(kbase + (size_t)(st * 64 + kr) * 64 + c4);
        *(float4*)&Ks[kr][c4] = kv;
      }
      __syncthreads();
      #pragma unroll
      for (int ssl = 0; ssl < 2; ++ssl) {
        const int lrow = c + 32 * ssl;
        float sum = 0.f;
        #pragma unroll
        for (int d4 = 0; d4 < 16; ++d4) {
          float4 kv = *(const float4*)&Ks[lrow][d4 * 4];
          sum += qv[d4].x * kv.x;
          sum += qv[d4].y * kv.y;
          sum += qv[d4].z * kv.z;
          sum += qv[d4].w * kv.w;
        }
        sc[st * 2 + ssl] = sum * 0.125f;   // 1/sqrt(64)
      }
    }
    // softmax over S: 32 regs x 32 lanes
    float m = sc[0];
    #pragma unroll
    for (int i = 1; i < 32; ++i) m = fmaxf(m, sc[i]);
    #pragma unroll
    for (int off = 16; off > 0; off >>= 1) m = fmaxf(m, __shfl_xor(m, off));
    float s = 0.f;
    #pragma unroll
    for (int i = 0; i < 32; ++i) { float p = __expf(sc[i] - m); sc[i] = p; s += p; }
    #pragma unroll
    for (int off = 16; off > 0; off >>= 1) s += __shfl_xor(s, off);
    const float f = 0.125f / s;   // fold 1/H into the accumulation
    #pragma unroll
    for (int i = 0; i < 32; ++i) acc[i] += sc[i] * f;
  }

  // threshold > 0.1, renormalize by (sum + 1e-6)
  float ts = 0.f;
  #pragma unroll
  for (int i = 0; i < 32; ++i) {
    const float v = acc[i] > THRESH ? acc[i] : 0.f;
    acc[i] = v;
    ts += v;
  }
  #pragma unroll
  for (int off = 16; off > 0; off >>= 1) ts += __shfl_xor(ts, off);
  const float inv = 1.f / (ts + 1e-6f);
  float* swrow = sw + (size_t)(b * 1024 + l0 + r) * 1024 + c;
  #pragma unroll
  for (int i = 0; i < 32; ++i) swrow[i * 32] = acc[i] * inv;
}

// ---------------------------------------------------------------------------
// K3: sparse PV. Each sw row has <=9 nonzeros (values >0.1, row-sum~1).
// Block per (l,b): scan row, build (s,w) list in LDS, gather value rows.
// out[l][b][e] = sum_j w_j * value[s_j][b][e].
// ---------------------------------------------------------------------------
__global__ __launch_bounds__(128) void pv_kernel(
    const float* __restrict__ sw,     // [B][L][S]
    const float* __restrict__ value,  // [S][B][E]
    float* __restrict__ out)          // [L][B][E]
{
  const int l = blockIdx.x;
  const int b = blockIdx.y;
  const int t = threadIdx.x;
  __shared__ int cnt;
  __shared__ int   sidx[32];
  __shared__ float swt[32];
  if (t == 0) cnt = 0;
  __syncthreads();

  const float* row = sw + (size_t)(b * 1024 + l) * 1024;
  #pragma unroll
  for (int it = 0; it < 2; ++it) {
    const int s0 = (t + it * 128) * 4;
    float4 v = *(const float4*)(row + s0);
    if (v.x > 0.f) { int i = atomicAdd(&cnt, 1); if (i < 32) { sidx[i] = s0 + 0; swt[i] = v.x; } }
    if (v.y > 0.f) { int i = atomicAdd(&cnt, 1); if (i < 32) { sidx[i] = s0 + 1; swt[i] = v.y; } }
    if (v.z > 0.f) { int i = atomicAdd(&cnt, 1); if (i < 32) { sidx[i] = s0 + 2; swt[i] = v.z; } }
    if (v.w > 0.f) { int i = atomicAdd(&cnt, 1); if (i < 32) { sidx[i] = s0 + 3; swt[i] = v.w; } }
  }
  __syncthreads();
  const int n = cnt < 32 ? cnt : 32;

  const int e0 = t * 4;   // 128 threads x 4 = 512
  float4 o = {0.f, 0.f, 0.f, 0.f};
  for (int j = 0; j < n; ++j) {
    const float w = swt[j];
    const float4 vv = *(const float4*)(value + (size_t)(sidx[j] * 8 + b) * 512 + e0);
    o.x += w * vv.x; o.y += w * vv.y; o.z += w * vv.z; o.w += w * vv.w;
  }
  *(float4*)&out[(size_t)(l * 8 + b) * 512 + e0] = o;
}

// ---------------------------------------------------------------------------
extern "C" void kernel_launch(void* const* d_in, const int* in_sizes, int n_in,
                              void* d_out, int out_size, void* d_ws, size_t ws_size,
                              hipStream_t stream) {
  const float* query = (const float*)d_in[0];
  const float* key   = (const float*)d_in[1];
  const float* value = (const float*)d_in[2];
  const float* Wq    = (const float*)d_in[3];
  const float* bq    = (const float*)d_in[4];
  const float* Wk    = (const float*)d_in[5];
  const float* bk    = (const float*)d_in[6];

  float* out = (float*)d_out;                 // (L,B,E) = 4,194,304 floats
  float* sw  = out + (size_t)1024 * 8 * 512;  // (B,L,S) = 8,388,608 floats

  float* qws = (float*)d_ws;                       // [B][H][L][D] 16 MB
  float* kws = qws + (size_t)8 * 8 * 1024 * 64;    // [B][H][S][D] 16 MB

  proj_kernel<<<dim3(64, 4), 256, 0, stream>>>(query, Wq, bq, qws);
  proj_kernel<<<dim3(64, 4), 256, 0, stream>>>(key,   Wk, bk, kws);
  attn_kernel<<<dim3(128, 8), 256, 0, stream>>>(qws, kws, sw);
  pv_kernel<<<dim3(1024, 8), 128, 0, stream>>>(sw, value, out);
}

// Round 3
// 388.603 us; speedup vs baseline: 2.1003x; 2.1003x over previous
//
#include <hip/hip_runtime.h>

// SparseAttention on MI355X.
// R3: QK^T via 3-way bf16-split MFMA (6 terms -> fp32-equivalent precision,
// err ~2^-26 rel, below fp32 accum noise -> no threshold-flip risk).
// proj epilogue emits the 3 bf16 planes directly.

#define THRESH 0.1f
#define PLANE (8 * 8 * 1024 * 64)   // elements per split plane [B][H][L][D]

typedef __attribute__((ext_vector_type(8))) short bf8_t;  // 8 bf16 in 4 VGPRs
typedef __attribute__((ext_vector_type(4))) float f4_t;   // MFMA acc

#define MFMA16(a, b, c) __builtin_amdgcn_mfma_f32_16x16x32_bf16(a, b, c, 0, 0, 0)

__device__ __forceinline__ unsigned short f2bf(float x) {  // RNE
  unsigned int u = __float_as_uint(x);
  u += 0x7FFFu + ((u >> 16) & 1u);
  return (unsigned short)(u >> 16);
}
__device__ __forceinline__ float bf2f(unsigned short h) {
  return __uint_as_float(((unsigned int)h) << 16);
}

// ---------------------------------------------------------------------------
// K1: projection GEMM  out = A @ W^T + bias -> 3 bf16 split planes [B][H][L][D]
// ---------------------------------------------------------------------------
__global__ __launch_bounds__(256) void proj_kernel(
    const float* __restrict__ A,
    const float* __restrict__ W,
    const float* __restrict__ bias,
    unsigned short* __restrict__ outp)   // 3 planes, stride PLANE
{
  __shared__ float As[16][132];
  __shared__ float Ws[16][132];
  const int t  = threadIdx.x;
  const int bm = blockIdx.x;
  const int bn = blockIdx.y;
  const int ty = t >> 4;
  const int tx = t & 15;
  const int lr  = t >> 2;
  const int lc4 = (t & 3) << 2;

  const float* Arow0 = A + (size_t)(bm * 128 + lr) * 512 + lc4;
  const float* Arow1 = Arow0 + 64 * 512;
  const float* Wrow0 = W + (size_t)(bn * 128 + lr) * 512 + lc4;
  const float* Wrow1 = Wrow0 + 64 * 512;

  float acc[8][8] = {};

  for (int k0 = 0; k0 < 512; k0 += 16) {
    float4 a0 = *(const float4*)(Arow0 + k0);
    float4 a1 = *(const float4*)(Arow1 + k0);
    float4 w0 = *(const float4*)(Wrow0 + k0);
    float4 w1 = *(const float4*)(Wrow1 + k0);
    __syncthreads();
    As[lc4 + 0][lr] = a0.x; As[lc4 + 1][lr] = a0.y; As[lc4 + 2][lr] = a0.z; As[lc4 + 3][lr] = a0.w;
    As[lc4 + 0][lr + 64] = a1.x; As[lc4 + 1][lr + 64] = a1.y; As[lc4 + 2][lr + 64] = a1.z; As[lc4 + 3][lr + 64] = a1.w;
    Ws[lc4 + 0][lr] = w0.x; Ws[lc4 + 1][lr] = w0.y; Ws[lc4 + 2][lr] = w0.z; Ws[lc4 + 3][lr] = w0.w;
    Ws[lc4 + 0][lr + 64] = w1.x; Ws[lc4 + 1][lr + 64] = w1.y; Ws[lc4 + 2][lr + 64] = w1.z; Ws[lc4 + 3][lr + 64] = w1.w;
    __syncthreads();
    #pragma unroll
    for (int kk = 0; kk < 16; ++kk) {
      float4 av0 = *(const float4*)&As[kk][ty * 8];
      float4 av1 = *(const float4*)&As[kk][ty * 8 + 4];
      float4 bv0 = *(const float4*)&Ws[kk][tx * 8];
      float4 bv1 = *(const float4*)&Ws[kk][tx * 8 + 4];
      float ar[8] = {av0.x, av0.y, av0.z, av0.w, av1.x, av1.y, av1.z, av1.w};
      float br[8] = {bv0.x, bv0.y, bv0.z, bv0.w, bv1.x, bv1.y, bv1.z, bv1.w};
      #pragma unroll
      for (int i = 0; i < 8; ++i)
        #pragma unroll
        for (int j = 0; j < 8; ++j)
          acc[i][j] += ar[i] * br[j];
    }
  }

  #pragma unroll
  for (int i = 0; i < 8; ++i) {
    const int gr = bm * 128 + ty * 8 + i;
    const int l = gr >> 3;
    const int b = gr & 7;
    #pragma unroll
    for (int jv = 0; jv < 8; jv += 4) {
      const int gc = bn * 128 + tx * 8 + jv;
      const int h = gc >> 6;
      const int d = gc & 63;
      const size_t off = ((size_t)((b * 8 + h) * 1024 + l)) * 64 + d;
      ushort4 ph, pm, pl;
      #pragma unroll
      for (int q = 0; q < 4; ++q) {
        float x = acc[i][jv + q] + bias[gc + q];
        unsigned short b1 = f2bf(x);  float r1 = x  - bf2f(b1);
        unsigned short b2 = f2bf(r1); float r2 = r1 - bf2f(b2);
        unsigned short b3 = f2bf(r2);
        ((unsigned short*)&ph)[q] = b1;
        ((unsigned short*)&pm)[q] = b2;
        ((unsigned short*)&pl)[q] = b3;
      }
      *(ushort4*)&outp[off] = ph;
      *(ushort4*)&outp[(size_t)PLANE + off] = pm;
      *(ushort4*)&outp[(size_t)2 * PLANE + off] = pl;
    }
  }
}

// ---------------------------------------------------------------------------
// K2: MFMA attention. Block = (b, 32 q-rows), 512 thr / 8 waves.
// Wave w owns s-cols [w*128, w*128+128). Per head: 6-term split QK^T into
// f32 acc, cross-wave softmax via LDS, attn_avg accumulated in regs.
// Epilogue: threshold>0.1, renorm, write sw[B][L][S].
// C/D layout (m89): col = lane&15, row = 4*(lane>>4) + reg.
// ---------------------------------------------------------------------------
__global__ __launch_bounds__(512, 2) void attn_mfma_kernel(
    const unsigned short* __restrict__ qs,  // 3 planes [B][H][L][64]
    const unsigned short* __restrict__ ks,  // 3 planes [B][H][S][64]
    float* __restrict__ sw)                 // [B][L][S]
{
  const int bx = blockIdx.x;
  const int b  = bx & 7;            // same-b blocks -> same XCD (L2-resident K)
  const int l0 = (bx >> 3) << 5;    // 32 q-rows
  const int tid  = threadIdx.x;
  const int w    = tid >> 6;        // wave 0..7
  const int lane = tid & 63;
  const int c    = lane & 15;       // A-row / B-col / C-col
  const int g    = lane >> 4;       // k-slice group; C-rows 4g..4g+3

  __shared__ float red[8][32];
  __shared__ float redc[32];

  f4_t avg[2][8];
  #pragma unroll
  for (int rt = 0; rt < 2; ++rt)
    #pragma unroll
    for (int ct = 0; ct < 8; ++ct)
      avg[rt][ct] = (f4_t){0.f, 0.f, 0.f, 0.f};

  for (int h = 0; h < 8; ++h) {
    const size_t qbase = ((size_t)((b * 8 + h) * 1024 + l0)) * 64;
    const size_t kbase = ((size_t)((b * 8 + h) * 1024)) * 64;

    // A fragments: [plane][rt][kc]
    bf8_t qf[3][2][2];
    #pragma unroll
    for (int p = 0; p < 3; ++p)
      #pragma unroll
      for (int rt = 0; rt < 2; ++rt)
        #pragma unroll
        for (int kc = 0; kc < 2; ++kc)
          qf[p][rt][kc] = *(const bf8_t*)&qs[(size_t)p * PLANE + qbase +
                                             (size_t)(rt * 16 + c) * 64 + kc * 32 + g * 8];

    f4_t acc[2][8];
    #pragma unroll
    for (int rt = 0; rt < 2; ++rt)
      #pragma unroll
      for (int ct = 0; ct < 8; ++ct)
        acc[rt][ct] = (f4_t){0.f, 0.f, 0.f, 0.f};

    #pragma unroll
    for (int ct = 0; ct < 8; ++ct) {
      const size_t kb = kbase + (size_t)(w * 128 + ct * 16 + c) * 64 + g * 8;
      #pragma unroll
      for (int kc = 0; kc < 2; ++kc) {
        bf8_t kh = *(const bf8_t*)&ks[kb + kc * 32];
        bf8_t km = *(const bf8_t*)&ks[(size_t)PLANE + kb + kc * 32];
        bf8_t kl = *(const bf8_t*)&ks[(size_t)2 * PLANE + kb + kc * 32];
        #pragma unroll
        for (int rt = 0; rt < 2; ++rt) {
          acc[rt][ct] = MFMA16(qf[0][rt][kc], kh, acc[rt][ct]);  // hh
          acc[rt][ct] = MFMA16(qf[0][rt][kc], km, acc[rt][ct]);  // hm
          acc[rt][ct] = MFMA16(qf[1][rt][kc], kh, acc[rt][ct]);  // mh
          acc[rt][ct] = MFMA16(qf[0][rt][kc], kl, acc[rt][ct]);  // hl
          acc[rt][ct] = MFMA16(qf[1][rt][kc], km, acc[rt][ct]);  // mm
          acc[rt][ct] = MFMA16(qf[2][rt][kc], kh, acc[rt][ct]);  // lh
        }
      }
    }

    // ---- row max (raw scores; scale folded into exp) ----
    float mloc[2][4];
    #pragma unroll
    for (int rt = 0; rt < 2; ++rt)
      #pragma unroll
      for (int reg = 0; reg < 4; ++reg) {
        float m = acc[rt][0][reg];
        #pragma unroll
        for (int ct = 1; ct < 8; ++ct) m = fmaxf(m, acc[rt][ct][reg]);
        #pragma unroll
        for (int off = 8; off > 0; off >>= 1) m = fmaxf(m, __shfl_xor(m, off));
        mloc[rt][reg] = m;
      }
    if (c == 0) {
      #pragma unroll
      for (int rt = 0; rt < 2; ++rt)
        #pragma unroll
        for (int reg = 0; reg < 4; ++reg)
          red[w][rt * 16 + g * 4 + reg] = mloc[rt][reg];
    }
    __syncthreads();
    if (tid < 32) {
      float m = red[0][tid];
      #pragma unroll
      for (int w2 = 1; w2 < 8; ++w2) m = fmaxf(m, red[w2][tid]);
      redc[tid] = m;
    }
    __syncthreads();
    float mrow[2][4];
    #pragma unroll
    for (int rt = 0; rt < 2; ++rt)
      #pragma unroll
      for (int reg = 0; reg < 4; ++reg)
        mrow[rt][reg] = redc[rt * 16 + g * 4 + reg];

    // ---- exp + row sum ----
    float sloc[2][4] = {};
    #pragma unroll
    for (int rt = 0; rt < 2; ++rt)
      #pragma unroll
      for (int ct = 0; ct < 8; ++ct)
        #pragma unroll
        for (int reg = 0; reg < 4; ++reg) {
          float p = __expf(0.125f * (acc[rt][ct][reg] - mrow[rt][reg]));
          acc[rt][ct][reg] = p;
          sloc[rt][reg] += p;
        }
    #pragma unroll
    for (int rt = 0; rt < 2; ++rt)
      #pragma unroll
      for (int reg = 0; reg < 4; ++reg) {
        float s = sloc[rt][reg];
        #pragma unroll
        for (int off = 8; off > 0; off >>= 1) s += __shfl_xor(s, off);
        sloc[rt][reg] = s;
      }
    if (c == 0) {
      #pragma unroll
      for (int rt = 0; rt < 2; ++rt)
        #pragma unroll
        for (int reg = 0; reg < 4; ++reg)
          red[w][rt * 16 + g * 4 + reg] = sloc[rt][reg];
    }
    __syncthreads();
    if (tid < 32) {
      float s = red[0][tid];
      #pragma unroll
      for (int w2 = 1; w2 < 8; ++w2) s += red[w2][tid];
      redc[tid] = s;
    }
    __syncthreads();
    #pragma unroll
    for (int rt = 0; rt < 2; ++rt)
      #pragma unroll
      for (int reg = 0; reg < 4; ++reg) {
        const float inv = 0.125f / redc[rt * 16 + g * 4 + reg];  // 1/(8*sum)
        #pragma unroll
        for (int ct = 0; ct < 8; ++ct)
          avg[rt][ct][reg] += acc[rt][ct][reg] * inv;
      }
  }

  // ---- threshold + renormalize + store ----
  float tl[2][4] = {};
  #pragma unroll
  for (int rt = 0; rt < 2; ++rt)
    #pragma unroll
    for (int ct = 0; ct < 8; ++ct)
      #pragma unroll
      for (int reg = 0; reg < 4; ++reg) {
        float v = avg[rt][ct][reg];
        v = v > THRESH ? v : 0.f;
        avg[rt][ct][reg] = v;
        tl[rt][reg] += v;
      }
  #pragma unroll
  for (int rt = 0; rt < 2; ++rt)
    #pragma unroll
    for (int reg = 0; reg < 4; ++reg) {
      float s = tl[rt][reg];
      #pragma unroll
      for (int off = 8; off > 0; off >>= 1) s += __shfl_xor(s, off);
      tl[rt][reg] = s;
    }
  if (c == 0) {
    #pragma unroll
    for (int rt = 0; rt < 2; ++rt)
      #pragma unroll
      for (int reg = 0; reg < 4; ++reg)
        red[w][rt * 16 + g * 4 + reg] = tl[rt][reg];
  }
  __syncthreads();
  if (tid < 32) {
    float s = red[0][tid];
    #pragma unroll
    for (int w2 = 1; w2 < 8; ++w2) s += red[w2][tid];
    redc[tid] = s;
  }
  __syncthreads();
  #pragma unroll
  for (int rt = 0; rt < 2; ++rt)
    #pragma unroll
    for (int reg = 0; reg < 4; ++reg) {
      const float inv = 1.f / (redc[rt * 16 + g * 4 + reg] + 1e-6f);
      const size_t rowoff = ((size_t)(b * 1024 + l0 + rt * 16 + g * 4 + reg)) * 1024;
      #pragma unroll
      for (int ct = 0; ct < 8; ++ct)
        sw[rowoff + w * 128 + ct * 16 + c] = avg[rt][ct][reg] * inv;
    }
}

// ---------------------------------------------------------------------------
// K3: sparse PV (<=9 nnz/row guaranteed by threshold 0.1 + row-sum<=1).
// ---------------------------------------------------------------------------
__global__ __launch_bounds__(128) void pv_kernel(
    const float* __restrict__ sw,
    const float* __restrict__ value,
    float* __restrict__ out)
{
  const int l = blockIdx.x;
  const int b = blockIdx.y;
  const int t = threadIdx.x;
  __shared__ int cnt;
  __shared__ int   sidx[32];
  __shared__ float swt[32];
  if (t == 0) cnt = 0;
  __syncthreads();

  const float* row = sw + (size_t)(b * 1024 + l) * 1024;
  #pragma unroll
  for (int it = 0; it < 2; ++it) {
    const int s0 = (t + it * 128) * 4;
    float4 v = *(const float4*)(row + s0);
    if (v.x > 0.f) { int i = atomicAdd(&cnt, 1); if (i < 32) { sidx[i] = s0 + 0; swt[i] = v.x; } }
    if (v.y > 0.f) { int i = atomicAdd(&cnt, 1); if (i < 32) { sidx[i] = s0 + 1; swt[i] = v.y; } }
    if (v.z > 0.f) { int i = atomicAdd(&cnt, 1); if (i < 32) { sidx[i] = s0 + 2; swt[i] = v.z; } }
    if (v.w > 0.f) { int i = atomicAdd(&cnt, 1); if (i < 32) { sidx[i] = s0 + 3; swt[i] = v.w; } }
  }
  __syncthreads();
  const int n = cnt < 32 ? cnt : 32;

  const int e0 = t * 4;
  float4 o = {0.f, 0.f, 0.f, 0.f};
  for (int j = 0; j < n; ++j) {
    const float wgt = swt[j];
    const float4 vv = *(const float4*)(value + (size_t)(sidx[j] * 8 + b) * 512 + e0);
    o.x += wgt * vv.x; o.y += wgt * vv.y; o.z += wgt * vv.z; o.w += wgt * vv.w;
  }
  *(float4*)&out[(size_t)(l * 8 + b) * 512 + e0] = o;
}

// ---------------------------------------------------------------------------
extern "C" void kernel_launch(void* const* d_in, const int* in_sizes, int n_in,
                              void* d_out, int out_size, void* d_ws, size_t ws_size,
                              hipStream_t stream) {
  const float* query = (const float*)d_in[0];
  const float* key   = (const float*)d_in[1];
  const float* value = (const float*)d_in[2];
  const float* Wq    = (const float*)d_in[3];
  const float* bq    = (const float*)d_in[4];
  const float* Wk    = (const float*)d_in[5];
  const float* bk    = (const float*)d_in[6];

  float* out = (float*)d_out;
  float* sw  = out + (size_t)1024 * 8 * 512;

  unsigned short* qs = (unsigned short*)d_ws;          // 3 planes, 24 MB
  unsigned short* ks = qs + (size_t)3 * PLANE;         // 3 planes, 24 MB

  proj_kernel<<<dim3(64, 4), 256, 0, stream>>>(query, Wq, bq, qs);
  proj_kernel<<<dim3(64, 4), 256, 0, stream>>>(key,   Wk, bk, ks);
  attn_mfma_kernel<<<256, 512, 0, stream>>>(qs, ks, sw);
  pv_kernel<<<dim3(1024, 8), 128, 0, stream>>>(sw, value, out);
}